// Round 1
// baseline (1068.235 us; speedup 1.0000x reference)
//
#include <hip/hip_runtime.h>
#include <stdint.h>

#define N_CLUSTERS 100
#define M 10
#define HS 5
#define HM 50
#define GROUP 64          // batch elements per block
#define XPITCH 1004       // bf16 per row: 1000 + pad -> 2008 B (8B-aligned, 2-way bank = free)
#define EPITCH 101        // fp32 per err row (odd -> conflict-free)
#define HPITCH 52         // bf16 per hm row -> 104 B (26 words, 2-way = free)

// LDS layout (bytes):
//   xg   : 64*2008         = 128512  @ 0
//   err  : 64*101*4        =  25856  @ 128512
//   hm   : 64*52*2         =   6656  @ 154368
//   part : 4*64*4          =   1024  @ 161024
//   total                  = 162048  (<= 163840)
#define LDS_XG    0
#define LDS_ERR   128512
#define LDS_HM    154368
#define LDS_PART  161024
#define LDS_TOTAL 162048

__device__ __forceinline__ uint32_t f2bf(float f) {
    uint32_t u = __float_as_uint(f);
    return (u + 0x7fffu + ((u >> 16) & 1u)) >> 16;   // RNE
}
__device__ __forceinline__ float bf2f(uint32_t h) {
    return __uint_as_float(h << 16);
}

__global__ void __launch_bounds__(256, 1) kitnet_kernel(
    const float* __restrict__ x,
    const int*   __restrict__ fi,
    const float* __restrict__ W_enc, const float* __restrict__ b_enc,
    const float* __restrict__ W_dec, const float* __restrict__ b_dec,
    const float* __restrict__ We1,   const float* __restrict__ be1,
    const float* __restrict__ Wd1,   const float* __restrict__ bd1,
    float* __restrict__ out)
{
    extern __shared__ char smem[];
    ushort* xg   = (ushort*)(smem + LDS_XG);
    float*  errs = (float*) (smem + LDS_ERR);
    ushort* hmb  = (ushort*)(smem + LDS_HM);
    float*  part = (float*) (smem + LDS_PART);

    const int tid  = threadIdx.x;
    const int lane = tid & 63;
    const int w    = __builtin_amdgcn_readfirstlane(tid >> 6);  // force wave-uniform -> SGPR
    const int b0   = blockIdx.x * GROUP;

    // ---- stage: 64 rows x 1000 fp32 (contiguous 256 KB, coalesced) -> bf16 in LDS ----
    const float4* xr = (const float4*)(x + (size_t)b0 * 1000);
    for (int i = tid; i < 16000; i += 256) {
        float4 v = xr[i];
        int row = i / 250;               // compiler magic-mul
        int c4  = i - row * 250;
        uint32_t lo = f2bf(v.x) | (f2bf(v.y) << 16);
        uint32_t hi = f2bf(v.z) | (f2bf(v.w) << 16);
        *(uint2*)(smem + row * 2008 + c4 * 8) = make_uint2(lo, hi);
    }
    __syncthreads();

    // ---- cluster AEs: wave w handles clusters [25w, 25w+25); lane = element ----
    const int c0 = w * 25;
    const ushort* myrow = xg + lane * XPITCH;
    for (int c = c0; c < c0 + 25; ++c) {
        float xv[M];
        #pragma unroll
        for (int m = 0; m < M; ++m) {
            int col = fi[c * M + m];               // wave-uniform -> s_load
            xv[m] = bf2f(myrow[col]);
        }
        float h[HS];
        #pragma unroll
        for (int k = 0; k < HS; ++k) h[k] = b_enc[c * HS + k];
        #pragma unroll
        for (int m = 0; m < M; ++m) {
            #pragma unroll
            for (int k = 0; k < HS; ++k)
                h[k] = __builtin_fmaf(xv[m], W_enc[(c * M + m) * HS + k], h[k]);
        }
        #pragma unroll
        for (int k = 0; k < HS; ++k) h[k] = fmaxf(h[k], 0.f);

        float acc = 0.f;
        #pragma unroll
        for (int m = 0; m < M; ++m) {
            float r = b_dec[c * M + m];
            #pragma unroll
            for (int k = 0; k < HS; ++k)
                r = __builtin_fmaf(h[k], W_dec[(c * HS + k) * M + m], r);
            float d = xv[m] - r;
            acc = __builtin_fmaf(d, d, acc);
        }
        errs[lane * EPITCH + c] = __builtin_sqrtf(acc * 0.1f);
    }
    __syncthreads();

    // ---- meta encoder: wave w computes hm[j] for j in [13w, min(13w+13,50)) ----
    const int jb = w * 13;
    float hacc[13];
    #pragma unroll
    for (int j = 0; j < 13; ++j)
        hacc[j] = (jb + j < HM) ? be1[jb + j] : 0.f;
    const float* erow = errs + lane * EPITCH;
    for (int c = 0; c < N_CLUSTERS; ++c) {
        float e = erow[c];
        #pragma unroll
        for (int j = 0; j < 13; ++j)
            if (jb + j < HM)
                hacc[j] = __builtin_fmaf(e, We1[c * HM + jb + j], hacc[j]);
    }
    #pragma unroll
    for (int j = 0; j < 13; ++j)
        if (jb + j < HM)
            hmb[lane * HPITCH + jb + j] = (ushort)f2bf(fmaxf(hacc[j], 0.f));
    __syncthreads();

    // ---- meta decoder + final RMS: wave w handles its 25 clusters again ----
    float hv[HM];
    const uint32_t* hrow32 = (const uint32_t*)(hmb + lane * HPITCH);
    #pragma unroll
    for (int p = 0; p < 25; ++p) {
        uint32_t u = hrow32[p];
        hv[2 * p]     = bf2f(u & 0xffffu);
        hv[2 * p + 1] = bf2f(u >> 16);
    }
    float facc = 0.f;
    for (int c = c0; c < c0 + 25; ++c) {
        float e  = erow[c];
        float r0 = bd1[c], r1 = 0.f;   // 2 chains for FMA-latency ILP
        #pragma unroll
        for (int j = 0; j < HM; j += 2) {
            r0 = __builtin_fmaf(hv[j],     Wd1[j * N_CLUSTERS + c],       r0);
            r1 = __builtin_fmaf(hv[j + 1], Wd1[(j + 1) * N_CLUSTERS + c], r1);
        }
        float d = e - (r0 + r1);
        facc = __builtin_fmaf(d, d, facc);
    }
    part[tid] = facc;
    __syncthreads();

    if (tid < 64) {
        float s = part[tid] + part[tid + 64] + part[tid + 128] + part[tid + 192];
        float fe = __builtin_sqrtf(s * 0.01f);
        out[b0 + tid] = 1.f / (1.f + __expf(-fe));
    }
}

extern "C" void kernel_launch(void* const* d_in, const int* in_sizes, int n_in,
                              void* d_out, int out_size, void* d_ws, size_t ws_size,
                              hipStream_t stream) {
    const float* x     = (const float*)d_in[0];
    const int*   fi    = (const int*)  d_in[1];
    const float* W_enc = (const float*)d_in[2];
    const float* b_enc = (const float*)d_in[3];
    const float* W_dec = (const float*)d_in[4];
    const float* b_dec = (const float*)d_in[5];
    const float* We1   = (const float*)d_in[6];
    const float* be1   = (const float*)d_in[7];
    const float* Wd1   = (const float*)d_in[8];
    const float* bd1   = (const float*)d_in[9];
    float* out = (float*)d_out;

    (void)hipFuncSetAttribute((const void*)kitnet_kernel,
                              hipFuncAttributeMaxDynamicSharedMemorySize, LDS_TOTAL);
    kitnet_kernel<<<65536 / GROUP, 256, LDS_TOTAL, stream>>>(
        x, fi, W_enc, b_enc, W_dec, b_dec, We1, be1, Wd1, bd1, out);
}

// Round 2
// 876.858 us; speedup vs baseline: 1.2183x; 1.2183x over previous
//
#include <hip/hip_runtime.h>
#include <stdint.h>

#define N_CLUSTERS 100
#define M 10
#define HS 5
#define HM 50
#define GROUP 64           // batch rows per block
#define NWAVE 16           // 1024 threads
#define XPITCH_B 2012      // bytes per staged bf16 row: 503 words (odd -> 2-way free)
#define EPITCH 101         // fp32 per err row (101%32=5, odd -> 2-way free)
#define HPITCH 52          // u16 per hm row (104 B, u32-aligned rows)

// LDS layout (bytes):
//   xg   : 64*2012 = 128768 @ 0        (aliased by part[16*64] f32 after cluster phase)
//   err  : 64*101*4 = 25856 @ 128768
//   hm   : 64*52*2  =  6656 @ 154624
//   total           = 161280 (<= 163840)
#define LDS_XG    0
#define LDS_ERR   128768
#define LDS_HM    154624
#define LDS_TOTAL 161280

__device__ __forceinline__ uint32_t f2bf(float f) {
    uint32_t u = __float_as_uint(f);
    return (u + 0x7fffu + ((u >> 16) & 1u)) >> 16;   // RNE
}
__device__ __forceinline__ float bf2f(uint32_t h) {
    return __uint_as_float(h << 16);
}

__global__ void __launch_bounds__(1024, 1) kitnet_kernel(
    const float* __restrict__ x,
    const int*   __restrict__ fi,
    const float* __restrict__ W_enc, const float* __restrict__ b_enc,
    const float* __restrict__ W_dec, const float* __restrict__ b_dec,
    const float* __restrict__ We1,   const float* __restrict__ be1,
    const float* __restrict__ Wd1,   const float* __restrict__ bd1,
    float* __restrict__ out)
{
    extern __shared__ char smem[];
    float*  errs = (float*) (smem + LDS_ERR);
    ushort* hmb  = (ushort*)(smem + LDS_HM);

    const int tid  = threadIdx.x;
    const int lane = tid & 63;
    const int w    = __builtin_amdgcn_readfirstlane(tid >> 6);  // wave id, SGPR
    const int b0   = blockIdx.x * GROUP;

    // ---- stage: 64 rows x 1000 fp32 (256 KB contiguous, coalesced) -> bf16 LDS ----
    const float4* xr = (const float4*)(x + (size_t)b0 * 1000);
    for (int i = tid; i < 16000; i += 1024) {
        float4 v = xr[i];
        int row = i / 250;
        int c4  = i - row * 250;
        char* p = smem + row * XPITCH_B + c4 * 8;
        *(uint32_t*)(p)     = f2bf(v.x) | (f2bf(v.y) << 16);
        *(uint32_t*)(p + 4) = f2bf(v.z) | (f2bf(v.w) << 16);
    }
    __syncthreads();

    // ---- cluster AEs: wave w -> clusters {w, w+16, ...}; lane = batch row ----
    const ushort* myrow = (const ushort*)(smem + lane * XPITCH_B);
    for (int c = w; c < N_CLUSTERS; c += NWAVE) {
        float xv[M];
        #pragma unroll
        for (int m = 0; m < M; ++m) {
            int col = fi[c * M + m];                  // wave-uniform -> s_load
            xv[m] = bf2f(myrow[col]);
        }
        float h[HS];
        #pragma unroll
        for (int k = 0; k < HS; ++k) h[k] = b_enc[c * HS + k];
        #pragma unroll
        for (int m = 0; m < M; ++m) {
            #pragma unroll
            for (int k = 0; k < HS; ++k)
                h[k] = __builtin_fmaf(xv[m], W_enc[(c * M + m) * HS + k], h[k]);
        }
        #pragma unroll
        for (int k = 0; k < HS; ++k) h[k] = fmaxf(h[k], 0.f);

        float acc = 0.f;
        #pragma unroll
        for (int m = 0; m < M; ++m) {
            float r = b_dec[c * M + m];
            #pragma unroll
            for (int k = 0; k < HS; ++k)
                r = __builtin_fmaf(h[k], W_dec[(c * HS + k) * M + m], r);
            float d = xv[m] - r;
            acc = __builtin_fmaf(d, d, acc);
        }
        errs[lane * EPITCH + c] = __builtin_sqrtf(acc * 0.1f);
    }
    __syncthreads();

    // ---- meta encoder: wave w -> hidden units j = w + 16*i (i<4, j<50) ----
    const float* erow = errs + lane * EPITCH;
    {
        float hacc[4];
        #pragma unroll
        for (int i = 0; i < 4; ++i) {
            int j = w + NWAVE * i;
            hacc[i] = (j < HM) ? be1[j] : 0.f;
        }
        #pragma unroll 4
        for (int c = 0; c < N_CLUSTERS; ++c) {
            float e = erow[c];
            #pragma unroll
            for (int i = 0; i < 4; ++i) {
                int j = w + NWAVE * i;
                if (j < HM)
                    hacc[i] = __builtin_fmaf(e, We1[c * HM + j], hacc[i]);
            }
        }
        #pragma unroll
        for (int i = 0; i < 4; ++i) {
            int j = w + NWAVE * i;
            if (j < HM)
                hmb[lane * HPITCH + j] = (ushort)f2bf(fmaxf(hacc[i], 0.f));
        }
    }
    __syncthreads();

    // ---- meta decoder + final RMS: wave w -> same clusters {w, w+16, ...} ----
    float acc[7];
    #pragma unroll
    for (int i = 0; i < 7; ++i) acc[i] = 0.f;
    const uint32_t* hrow32 = (const uint32_t*)(hmb + lane * HPITCH);
    #pragma unroll
    for (int jc = 0; jc < 5; ++jc) {               // hm chunks of 10
        float hv[10];
        #pragma unroll
        for (int p = 0; p < 5; ++p) {
            uint32_t u = hrow32[jc * 5 + p];
            hv[2 * p]     = bf2f(u & 0xffffu);
            hv[2 * p + 1] = bf2f(u >> 16);
        }
        #pragma unroll
        for (int jj = 0; jj < 10; ++jj) {
            int j = jc * 10 + jj;
            #pragma unroll
            for (int i = 0; i < 7; ++i) {
                int c = w + NWAVE * i;
                if (c < N_CLUSTERS)
                    acc[i] = __builtin_fmaf(hv[jj], Wd1[j * N_CLUSTERS + c], acc[i]);
            }
        }
    }
    float facc = 0.f;
    #pragma unroll
    for (int i = 0; i < 7; ++i) {
        int c = w + NWAVE * i;
        if (c < N_CLUSTERS) {
            float e = erow[c];
            float d = e - (acc[i] + bd1[c]);
            facc = __builtin_fmaf(d, d, facc);
        }
    }

    // ---- reduce 16 wave-partials per row (part aliases dead xg region) ----
    float* part = (float*)smem;
    part[w * 64 + lane] = facc;
    __syncthreads();
    if (tid < 64) {
        float s = 0.f;
        #pragma unroll
        for (int i = 0; i < NWAVE; ++i) s += part[i * 64 + tid];
        float fe = __builtin_sqrtf(s * 0.01f);
        out[b0 + tid] = 1.f / (1.f + __expf(-fe));
    }
}

extern "C" void kernel_launch(void* const* d_in, const int* in_sizes, int n_in,
                              void* d_out, int out_size, void* d_ws, size_t ws_size,
                              hipStream_t stream) {
    const float* x     = (const float*)d_in[0];
    const int*   fi    = (const int*)  d_in[1];
    const float* W_enc = (const float*)d_in[2];
    const float* b_enc = (const float*)d_in[3];
    const float* W_dec = (const float*)d_in[4];
    const float* b_dec = (const float*)d_in[5];
    const float* We1   = (const float*)d_in[6];
    const float* be1   = (const float*)d_in[7];
    const float* Wd1   = (const float*)d_in[8];
    const float* bd1   = (const float*)d_in[9];
    float* out = (float*)d_out;

    (void)hipFuncSetAttribute((const void*)kitnet_kernel,
                              hipFuncAttributeMaxDynamicSharedMemorySize, LDS_TOTAL);
    kitnet_kernel<<<65536 / GROUP, 1024, LDS_TOTAL, stream>>>(
        x, fi, W_enc, b_enc, W_dec, b_dec, We1, be1, Wd1, bd1, out);
}